// Round 21
// baseline (120.801 us; speedup 1.0000x reference)
//
#include <hip/hip_runtime.h>
#include <hip/hip_bf16.h>

// Problem constants
#define BATCH 2
#define CIN   1024
#define NN    2048
#define HEADS 16
#define DHEAD 64
#define HDIM  1024
#define O3    3072
#define QSCALE 0.125f
// 0.125 * log2(e): Q pre-scale so softmax runs in exp2 domain
#define QSCALE_L2E 0.18033688011112042f
#define QSZ ((size_t)BATCH * HEADS * NN * DHEAD)  // 4,194,304 elements

typedef unsigned short ushort_t;
typedef __attribute__((ext_vector_type(8))) short bf16x8;
typedef __attribute__((ext_vector_type(8))) unsigned short ushort8;
typedef __attribute__((ext_vector_type(4))) unsigned short ushort4v;
typedef __attribute__((ext_vector_type(16))) float f32x16;

__device__ inline ushort_t f2bf(float f) {
    unsigned u = __builtin_bit_cast(unsigned, f);
    unsigned r = u + 0x7fffu + ((u >> 16) & 1u);
    return (ushort_t)(r >> 16);
}
__device__ inline float bf2f(ushort_t h) {
    return __builtin_bit_cast(float, (unsigned)h << 16);
}
__device__ inline f32x16 mfma32(bf16x8 a, bf16x8 b, f32x16 c) {
    return __builtin_amdgcn_mfma_f32_32x32x16_bf16(a, b, c, 0, 0, 0);
}
// packed 2xbf16 (RNE): low half = bf16(a), high half = bf16(b)
__device__ inline unsigned cvt_pk_bf16(float a, float b) {
    unsigned r;
    asm("v_cvt_pk_bf16_f32 %0, %1, %2" : "=v"(r) : "v"(a), "v"(b));
    return r;
}

union U4 { unsigned u[4]; bf16x8 v; };

// global -> LDS direct (16B per lane); LDS dest is wave-uniform base + lane*16
#define GLDS(gp, lp) __builtin_amdgcn_global_load_lds( \
    (__attribute__((address_space(1))) void*)(gp),     \
    (__attribute__((address_space(3))) void*)(lp), 16, 0, 0)

// ---------------- fused prep: w_qkv/w_out bf16 convert + x transpose ----------------
// blocks [0,2048): elementwise converts; blocks [2048,6144): x^T tiles.
__global__ __launch_bounds__(256) void prep_fused(const float* __restrict__ w1,
                                                  ushort_t* __restrict__ o1,
                                                  int n8_1,
                                                  const float* __restrict__ w2,
                                                  ushort_t* __restrict__ o2,
                                                  int n8_2,
                                                  const float* __restrict__ x,
                                                  ushort_t* __restrict__ xt) {
    if (blockIdx.x < 2048) {
        int t = blockIdx.x * 256 + threadIdx.x;
        const float* in = w1;
        ushort_t* out = o1;
        if (t >= n8_1) {
            t -= n8_1;
            if (t >= n8_2) return;
            in = w2;
            out = o2;
        }
        size_t base = (size_t)t * 8;
        float4 a = *(const float4*)(in + base);
        float4 b = *(const float4*)(in + base + 4);
        float v[8] = {a.x, a.y, a.z, a.w, b.x, b.y, b.z, b.w};
        ushort8 hv;
#pragma unroll
        for (int i = 0; i < 8; ++i) hv[i] = f2bf(v[i]);
        *(ushort8*)(out + base) = hv;
    } else {
        __shared__ float T[32][33];
        const int t6 = blockIdx.x - 2048;        // 0..4095
        const int b = t6 >> 11;                  // /2048
        const int rem = t6 & 2047;
        const int n0 = (rem & 63) * 32, c0 = (rem >> 6) * 32;
        const int t = threadIdx.x;
        const int r = t >> 3, q = t & 7;
        float4 v = *(const float4*)(x + ((size_t)b * CIN + c0 + r) * NN + n0 + q * 4);
        T[r][q * 4 + 0] = v.x; T[r][q * 4 + 1] = v.y;
        T[r][q * 4 + 2] = v.z; T[r][q * 4 + 3] = v.w;
        __syncthreads();
        ushort4v hv;
#pragma unroll
        for (int i = 0; i < 4; ++i) hv[i] = f2bf(T[q * 4 + i][r]);
        size_t o = ((size_t)b * NN + n0 + r) * CIN + c0 + q * 4;
        *(ushort4v*)(xt + o) = hv;
    }
}

// ---------------- MFMA GEMM (plain bf16, 1-term, both modes) ----------------
// MODE 0 (QKV): Q [bh][n][64] scaled 0.125*log2e; K/V FRAGMENT-MAJOR images.
// MODE 1 (out-proj): + bias -> f32 out.
template<int MODE>
__global__ __launch_bounds__(256, 3) void gemm_mfma(
    const ushort_t* __restrict__ Ah, const ushort_t* __restrict__ Bth,
    const float* __restrict__ bias, float* __restrict__ outF,
    ushort_t* __restrict__ Qh, ushort_t* __restrict__ Kf,
    ushort_t* __restrict__ Vf) {

    __shared__ __align__(16) ushort_t lsAh[4096], lsBh[4096];

    const int b  = blockIdx.z;
    const int n0 = blockIdx.x * 128;
    const int m0 = blockIdx.y * 128;
    const int tid = threadIdx.x;
    const int wave = tid >> 6, lane = tid & 63;
    const int l31 = lane & 31, hi5 = lane >> 5;
    const int wr = wave >> 1, wc = wave & 1;

    const int srow = lane >> 2;
    const int kswz = 8 * ((lane & 3) ^ ((lane >> 3) & 3));
    const ushort_t* gAh = Ah  + (size_t)(m0 + wave * 16 + srow) * CIN + kswz;
    const ushort_t* gBh = Bth + ((size_t)b * NN + n0 + wave * 16 + srow) * CIN + kswz;
    ushort_t* dAh = lsAh + wave * 512;
    ushort_t* dBh = lsBh + wave * 512;

    const int rswz = ((l31 >> 1) & 3) * 8;
    int offA[2][2], offB[2][2];
#pragma unroll
    for (int f = 0; f < 2; ++f)
#pragma unroll
        for (int kh = 0; kh < 2; ++kh) {
            offA[f][kh] = (wr * 64 + f * 32 + l31) * 64 + ((kh * 16 + hi5 * 8) ^ rswz) * 2;
            offB[f][kh] = (wc * 64 + f * 32 + l31) * 64 + ((kh * 16 + hi5 * 8) ^ rswz) * 2;
        }

    f32x16 acc[2][2];
#pragma unroll
    for (int i = 0; i < 2; ++i)
#pragma unroll
        for (int j = 0; j < 2; ++j)
#pragma unroll
            for (int r = 0; r < 16; ++r) acc[i][j][r] = 0.f;

    for (int k0 = 0; k0 < CIN; k0 += 32) {
        __syncthreads();
        GLDS(gAh + k0,            dAh);
        GLDS(gAh + 64 * CIN + k0, dAh + 2048);
        GLDS(gBh + k0,            dBh);
        GLDS(gBh + 64 * CIN + k0, dBh + 2048);
        __syncthreads();
#pragma unroll
        for (int kh = 0; kh < 2; ++kh) {
            bf16x8 a_h[2], b_h[2];
#pragma unroll
            for (int f = 0; f < 2; ++f) {
                a_h[f] = *(const bf16x8*)((const char*)lsAh + offA[f][kh]);
                b_h[f] = *(const bf16x8*)((const char*)lsBh + offB[f][kh]);
            }
#pragma unroll
            for (int fi = 0; fi < 2; ++fi)
#pragma unroll
                for (int fj = 0; fj < 2; ++fj)
                    acc[fi][fj] = mfma32(a_h[fi], b_h[fj], acc[fi][fj]);
        }
    }

    const int nn = n0 + wc * 64 + l31;

    if constexpr (MODE == 0) {
        const int region = m0 >> 10;  // 0=Q 1=K 2=V (uniform per block)
        if (region == 0) {
            const int head = ((m0 & 1023) >> 6) + wr;
            const size_t bh_base = (size_t)(b * HEADS + head) * NN;
#pragma unroll
            for (int fj = 0; fj < 2; ++fj) {
                const size_t rowb = (bh_base + nn + fj * 32) * DHEAD;
#pragma unroll
                for (int fi = 0; fi < 2; ++fi)
#pragma unroll
                    for (int g = 0; g < 4; ++g) {
                        ushort4v hv;
#pragma unroll
                        for (int i = 0; i < 4; ++i)
                            hv[i] = f2bf(acc[fi][fj][4 * g + i] * QSCALE_L2E);
                        *(ushort4v*)(Qh + rowb + fi * 32 + 4 * hi5 + 8 * g) = hv;
                    }
            }
        } else if (region == 1) {
            const int head = ((m0 & 1023) >> 6) + wr;
            const size_t bhk = (size_t)(b * HEADS + head);
#pragma unroll
            for (int fj = 0; fj < 2; ++fj) {
                const int j = nn + fj * 32;
                const size_t jbb = (bhk * 64 + (j >> 5)) * 4;
#pragma unroll
                for (int fi = 0; fi < 2; ++fi)
#pragma unroll
                    for (int g = 0; g < 4; ++g) {
                        ushort4v hv;
#pragma unroll
                        for (int i = 0; i < 4; ++i)
                            hv[i] = f2bf(acc[fi][fj][4 * g + i]);
                        const int c = fi * 2 + (g >> 1);
                        const int lk = (g & 1) * 32 + l31;
                        *(ushort4v*)(Kf + ((jbb + c) * 64 + lk) * 8 + 4 * hi5) = hv;
                    }
            }
        } else {
            const int ch0 = (m0 - 2048) + wr * 64;
#pragma unroll
            for (int fi = 0; fi < 2; ++fi)
#pragma unroll
                for (int fj = 0; fj < 2; ++fj) {
                    const int j = nn + fj * 32;
                    const int jb = j >> 5, kh2 = (j >> 4) & 1;
                    const int lvh = ((j >> 3) & 1) * 32;
                    const int e = j & 7;
#pragma unroll
                    for (int r = 0; r < 16; ++r) {
                        const int ch = ch0 + fi * 32 + (r & 3) + 8 * (r >> 2) + 4 * hi5;
                        const int head = ch >> 6, d = ch & 63;
                        const size_t idx =
                            (((((size_t)(b * HEADS + head) * 64 + jb) * 2 + kh2) * 2 +
                              (d >> 5)) * 64 + lvh + (d & 31)) * 8 + e;
                        Vf[idx] = f2bf(acc[fi][fj][r]);
                    }
                }
        }
    } else {
#pragma unroll
        for (int fi = 0; fi < 2; ++fi)
#pragma unroll
            for (int fj = 0; fj < 2; ++fj)
#pragma unroll
                for (int r = 0; r < 16; ++r) {
                    const int mrow = m0 + wr * 64 + fi * 32 + (r & 3) + 8 * (r >> 2) + 4 * hi5;
                    outF[((size_t)b * CIN + mrow) * NN + nn + fj * 32] =
                        acc[fi][fj][r] + bias[mrow];
                }
    }
}

// ---------------- MFMA flash attention v20 ----------------
// R18 structure (2 query-chains/wave, fragment-direct, in-block 2-way key
// split) + l-sum via MFMA ones-trick: l_vec = mfma(ones, pB, l_vec) replaces
// the 16-op VALU tree-sum per chain (VALU instruction count is the measured
// bottleneck); l = l_vec[0] is complete per query (no lane-half fold).
__global__ __launch_bounds__(256, 2) void attn_mfma(
    const ushort_t* __restrict__ Qh, const ushort_t* __restrict__ Kf,
    const ushort_t* __restrict__ Vf,
    ushort_t* __restrict__ aoth) {
    const int Lid = blockIdx.x;
    const int slot = Lid & 7, rest = Lid >> 3;
    const int bh = slot * 4 + (rest >> 4);
    const int qt = rest & 15;
    const int b = bh >> 4, h = bh & 15;
    const int w = threadIdx.x >> 6;        // 0..3
    const int team = w >> 1;               // 0: keys 0-1023, 1: 1024-2047
    const int qp = w & 1;                  // query pair within block
    const int lane = threadIdx.x & 63;
    const int l31 = lane & 31;
    const int hi5 = lane >> 5;
    const int q0a = qt * 128 + qp * 64;
    const int q0b = q0a + 32;

    __shared__ float oS[128 * 65];
    __shared__ float lS[128];

    // Q fragments for both chains (one-time gathers)
    bf16x8 qfa[4], qfb[4];
    {
        const ushort_t* qa = Qh + ((size_t)bh * NN + q0a + l31) * DHEAD + hi5 * 8;
        const ushort_t* qb = Qh + ((size_t)bh * NN + q0b + l31) * DHEAD + hi5 * 8;
#pragma unroll
        for (int c = 0; c < 4; ++c) {
            qfa[c] = *(const bf16x8*)(qa + c * 16);
            qfb[c] = *(const bf16x8*)(qb + c * 16);
        }
    }

    // ones fragment (bf16 1.0 x8) for MFMA l-sum
    U4 uo;
    uo.u[0] = 0x3F803F80u; uo.u[1] = 0x3F803F80u;
    uo.u[2] = 0x3F803F80u; uo.u[3] = 0x3F803F80u;
    const bf16x8 ones = uo.v;

    // fragment streams: 2048 elems (4KB) per 32-key block for each of K,V
    const ushort_t* kp0 = Kf + ((size_t)bh * 64 + team * 32) * 2048 + lane * 8;
    const ushort_t* vp0 = Vf + ((size_t)bh * 64 + team * 32) * 2048 + lane * 8;

    f32x16 o0a, o1a, o0b, o1b, lva, lvb, zz;
#pragma unroll
    for (int r = 0; r < 16; ++r) {
        o0a[r] = 0.f; o1a[r] = 0.f; o0b[r] = 0.f; o1b[r] = 0.f;
        lva[r] = 0.f; lvb[r] = 0.f; zz[r] = 0.f;
    }

#define ATTN_LOAD(P, JB)                                                       \
    {                                                                          \
        const ushort_t* kq_ = kp0 + (size_t)(JB) * 2048;                       \
        const ushort_t* vq_ = vp0 + (size_t)(JB) * 2048;                       \
        P##k0 = *(const bf16x8*)(kq_);                                         \
        P##k1 = *(const bf16x8*)(kq_ + 512);                                   \
        P##k2 = *(const bf16x8*)(kq_ + 1024);                                  \
        P##k3 = *(const bf16x8*)(kq_ + 1536);                                  \
        P##v0 = *(const bf16x8*)(vq_);                                         \
        P##v1 = *(const bf16x8*)(vq_ + 512);                                   \
        P##v2 = *(const bf16x8*)(vq_ + 1024);                                  \
        P##v3 = *(const bf16x8*)(vq_ + 1536);                                  \
    }

    // softmax + pack + PV + MFMA l-sum for one chain
#define ATTN_CHAIN(SS, V0, V1, V2, V3, O0, O1, LV)                             \
    {                                                                          \
        f32x16 s;                                                              \
        _Pragma("unroll") for (int r = 0; r < 16; ++r)                         \
            s[r] = __builtin_amdgcn_exp2f(SS[r]);                              \
        unsigned Q0 = cvt_pk_bf16(s[0], s[1]);                                 \
        unsigned Q1 = cvt_pk_bf16(s[2], s[3]);                                 \
        unsigned Q2 = cvt_pk_bf16(s[4], s[5]);                                 \
        unsigned Q3 = cvt_pk_bf16(s[6], s[7]);                                 \
        asm("v_permlane32_swap_b32 %0, %1" : "+v"(Q0), "+v"(Q2));              \
        asm("v_permlane32_swap_b32 %0, %1" : "+v"(Q1), "+v"(Q3));              \
        unsigned R0 = cvt_pk_bf16(s[8], s[9]);                                 \
        unsigned R1 = cvt_pk_bf16(s[10], s[11]);                               \
        unsigned R2 = cvt_pk_bf16(s[12], s[13]);                               \
        unsigned R3 = cvt_pk_bf16(s[14], s[15]);                               \
        asm("v_permlane32_swap_b32 %0, %1" : "+v"(R0), "+v"(R2));              \
        asm("v_permlane32_swap_b32 %0, %1" : "+v"(R1), "+v"(R3));              \
        U4 thA; thA.u[0] = Q0; thA.u[1] = Q1; thA.u[2] = Q2; thA.u[3] = Q3;    \
        U4 thB; thB.u[0] = R0; thB.u[1] = R1; thB.u[2] = R2; thB.u[3] = R3;    \
        bf16x8 pB0 = thA.v, pB1 = thB.v;                                       \
        __builtin_amdgcn_s_setprio(1);                                         \
        O0 = mfma32(V0, pB0, O0);                                              \
        O1 = mfma32(V1, pB0, O1);                                              \
        LV = mfma32(ones, pB0, LV);                                            \
        O0 = mfma32(V2, pB1, O0);                                              \
        O1 = mfma32(V3, pB1, O1);                                              \
        LV = mfma32(ones, pB1, LV);                                            \
        __builtin_amdgcn_s_setprio(0);                                         \
    }

#define ATTN_STEP2(K0, K1, K2, K3, V0, V1, V2, V3)                             \
    {                                                                          \
        __builtin_amdgcn_s_setprio(1);                                         \
        f32x16 sSa = mfma32(K0, qfa[0], zz);                                   \
        sSa = mfma32(K1, qfa[1], sSa);                                         \
        sSa = mfma32(K2, qfa[2], sSa);                                         \
        sSa = mfma32(K3, qfa[3], sSa);                                         \
        f32x16 sSb = mfma32(K0, qfb[0], zz);                                   \
        sSb = mfma32(K1, qfb[1], sSb);                                         \
        sSb = mfma32(K2, qfb[2], sSb);                                         \
        sSb = mfma32(K3, qfb[3], sSb);                                         \
        __builtin_amdgcn_s_setprio(0);                                         \
        ATTN_CHAIN(sSa, V0, V1, V2, V3, o0a, o1a, lva);                        \
        ATTN_CHAIN(sSb, V0, V1, V2, V3, o0b, o1b, lvb);                        \
    }

    bf16x8 ak0, ak1, ak2, ak3, av0, av1, av2, av3;
    bf16x8 bk0, bk1, bk2, bk3, bv0, bv1, bv2, bv3;
    ATTN_LOAD(a, 0);
#pragma unroll 1
    for (int jb = 0; jb < 32; jb += 2) {
        ATTN_LOAD(b, jb + 1);
        ATTN_STEP2(ak0, ak1, ak2, ak3, av0, av1, av2, av3);
        ATTN_LOAD(a, (jb + 2) & 31);
        ATTN_STEP2(bk0, bk1, bk2, bk3, bv0, bv1, bv2, bv3);
    }
#undef ATTN_LOAD
#undef ATTN_CHAIN
#undef ATTN_STEP2

    // ---- in-block combine (m=0 -> pure add), single barrier ----
    // l_vec rows all hold the full per-query sum; take row 0's register.
    const float la = lva[0];
    const float lb = lvb[0];
    const int qA = qp * 64 + l31;       // row within block's 128 queries
    const int qB = qA + 32;
    if (team == 1) {
#pragma unroll
        for (int dt = 0; dt < 2; ++dt)
#pragma unroll
            for (int r = 0; r < 16; ++r) {
                const int d = dt * 32 + (r & 3) + 8 * (r >> 2) + 4 * hi5;
                oS[qA * 65 + d] = dt ? o1a[r] : o0a[r];
                oS[qB * 65 + d] = dt ? o1b[r] : o0b[r];
            }
        if (hi5 == 0) { lS[qA] = la; lS[qB] = lb; }
    }
    __syncthreads();
    if (team == 0) {
        const float invlA = 1.0f / (la + lS[qA]);
        const float invlB = 1.0f / (lb + lS[qB]);
        const size_t rowa = ((size_t)b * NN + q0a + l31) * HDIM + h * DHEAD;
        const size_t rowbb = ((size_t)b * NN + q0b + l31) * HDIM + h * DHEAD;
#pragma unroll
        for (int dt = 0; dt < 2; ++dt)
#pragma unroll
            for (int g = 0; g < 4; ++g) {
                ushort4v hva, hvb;
#pragma unroll
                for (int i = 0; i < 4; ++i) {
                    const int r = 4 * g + i;
                    const int d = dt * 32 + i + 8 * g + 4 * hi5;
                    float fa = ((dt ? o1a[r] : o0a[r]) + oS[qA * 65 + d]) * invlA;
                    float fb = ((dt ? o1b[r] : o0b[r]) + oS[qB * 65 + d]) * invlB;
                    hva[i] = f2bf(fa);
                    hvb[i] = f2bf(fb);
                }
                const size_t oo = dt * 32 + 8 * g + 4 * hi5;
                *(ushort4v*)(aoth + rowa + oo) = hva;
                *(ushort4v*)(aoth + rowbb + oo) = hvb;
            }
    }
}

// ---------------- launch ----------------
extern "C" void kernel_launch(void* const* d_in, const int* in_sizes, int n_in,
                              void* d_out, int out_size, void* d_ws, size_t ws_size,
                              hipStream_t stream) {
    const float* x     = (const float*)d_in[0];
    const float* w_qkv = (const float*)d_in[1];
    const float* w_out = (const float*)d_in[2];
    const float* b_out = (const float*)d_in[3];
    float* out = (float*)d_out;

    ushort_t* ws_u = (ushort_t*)d_ws;
    ushort_t* Qh = ws_u;
    ushort_t* Kf = Qh + QSZ;                   // fragment-major K (8MB)
    ushort_t* Vf = Kf + QSZ;                   // fragment-major V (8MB)
    ushort_t* woh = ws_u + 3 * QSZ;            // w_out hi (free region)
    ushort_t* shared_u = ws_u + 6 * QSZ;       // wq hi (phase A), aot hi (phase B)
    ushort_t* wqh = shared_u;
    ushort_t* aoth = shared_u;
    ushort_t* xth = (ushort_t*)d_out;          // x^T bf16 in d_out (dead later)

    if (ws_size < (6 * QSZ + 2 * (size_t)BATCH * NN * CIN) * sizeof(ushort_t)) return;

    // 1) fused prep: w_qkv/w_out bf16 + x^T (concurrent, one launch)
    prep_fused<<<6144, 256, 0, stream>>>(w_qkv, wqh, O3 * CIN / 8,
                                         w_out, woh, CIN * HDIM / 8, x, xth);

    // 2) QKV projection (plain bf16) -> Q / Kf / Vf (fragment-major K,V)
    gemm_mfma<0><<<dim3(NN / 128, O3 / 128, BATCH), 256, 0, stream>>>(
        wqh, xth, nullptr, nullptr, Qh, Kf, Vf);

    // 3) flash attention (2 chains/wave, MFMA l-sum) -> aot hi
    attn_mfma<<<dim3(512), 256, 0, stream>>>(Qh, Kf, Vf, aoth);

    // 4) output projection (plain bf16 1-term) + bias -> out f32
    gemm_mfma<1><<<dim3(NN / 128, HDIM / 128, BATCH), 256, 0, stream>>>(
        woh, aoth, b_out, out, nullptr, nullptr, nullptr);
}

// Round 22
// 110.009 us; speedup vs baseline: 1.0981x; 1.0981x over previous
//
#include <hip/hip_runtime.h>
#include <hip/hip_bf16.h>

// Problem constants
#define BATCH 2
#define CIN   1024
#define NN    2048
#define HEADS 16
#define DHEAD 64
#define HDIM  1024
#define O3    3072
#define QSCALE 0.125f
// 0.125 * log2(e): Q pre-scale so softmax runs in exp2 domain
#define QSCALE_L2E 0.18033688011112042f
#define QSZ ((size_t)BATCH * HEADS * NN * DHEAD)  // 4,194,304 elements

typedef unsigned short ushort_t;
typedef __attribute__((ext_vector_type(8))) short bf16x8;
typedef __attribute__((ext_vector_type(8))) unsigned short ushort8;
typedef __attribute__((ext_vector_type(4))) unsigned short ushort4v;
typedef __attribute__((ext_vector_type(16))) float f32x16;

__device__ inline ushort_t f2bf(float f) {
    unsigned u = __builtin_bit_cast(unsigned, f);
    unsigned r = u + 0x7fffu + ((u >> 16) & 1u);
    return (ushort_t)(r >> 16);
}
__device__ inline float bf2f(ushort_t h) {
    return __builtin_bit_cast(float, (unsigned)h << 16);
}
__device__ inline f32x16 mfma32(bf16x8 a, bf16x8 b, f32x16 c) {
    return __builtin_amdgcn_mfma_f32_32x32x16_bf16(a, b, c, 0, 0, 0);
}
// packed 2xbf16 (RNE): low half = bf16(a), high half = bf16(b)
__device__ inline unsigned cvt_pk_bf16(float a, float b) {
    unsigned r;
    asm("v_cvt_pk_bf16_f32 %0, %1, %2" : "=v"(r) : "v"(a), "v"(b));
    return r;
}

union U4 { unsigned u[4]; bf16x8 v; };

// global -> LDS direct (16B per lane); LDS dest is wave-uniform base + lane*16
#define GLDS(gp, lp) __builtin_amdgcn_global_load_lds( \
    (__attribute__((address_space(1))) void*)(gp),     \
    (__attribute__((address_space(3))) void*)(lp), 16, 0, 0)

// ---------------- fused prep: w_qkv/w_out bf16 convert + x transpose ----------------
// blocks [0,2048): elementwise converts; blocks [2048,6144): x^T tiles.
__global__ __launch_bounds__(256) void prep_fused(const float* __restrict__ w1,
                                                  ushort_t* __restrict__ o1,
                                                  int n8_1,
                                                  const float* __restrict__ w2,
                                                  ushort_t* __restrict__ o2,
                                                  int n8_2,
                                                  const float* __restrict__ x,
                                                  ushort_t* __restrict__ xt) {
    if (blockIdx.x < 2048) {
        int t = blockIdx.x * 256 + threadIdx.x;
        const float* in = w1;
        ushort_t* out = o1;
        if (t >= n8_1) {
            t -= n8_1;
            if (t >= n8_2) return;
            in = w2;
            out = o2;
        }
        size_t base = (size_t)t * 8;
        float4 a = *(const float4*)(in + base);
        float4 b = *(const float4*)(in + base + 4);
        float v[8] = {a.x, a.y, a.z, a.w, b.x, b.y, b.z, b.w};
        ushort8 hv;
#pragma unroll
        for (int i = 0; i < 8; ++i) hv[i] = f2bf(v[i]);
        *(ushort8*)(out + base) = hv;
    } else {
        __shared__ float T[32][33];
        const int t6 = blockIdx.x - 2048;        // 0..4095
        const int b = t6 >> 11;                  // /2048
        const int rem = t6 & 2047;
        const int n0 = (rem & 63) * 32, c0 = (rem >> 6) * 32;
        const int t = threadIdx.x;
        const int r = t >> 3, q = t & 7;
        float4 v = *(const float4*)(x + ((size_t)b * CIN + c0 + r) * NN + n0 + q * 4);
        T[r][q * 4 + 0] = v.x; T[r][q * 4 + 1] = v.y;
        T[r][q * 4 + 2] = v.z; T[r][q * 4 + 3] = v.w;
        __syncthreads();
        ushort4v hv;
#pragma unroll
        for (int i = 0; i < 4; ++i) hv[i] = f2bf(T[q * 4 + i][r]);
        size_t o = ((size_t)b * NN + n0 + r) * CIN + c0 + q * 4;
        *(ushort4v*)(xt + o) = hv;
    }
}

// ---------------- MFMA GEMM (plain bf16, 1-term, both modes) ----------------
// MODE 0 (QKV): Q [bh][n][64] scaled 0.125*log2e; K/V FRAGMENT-MAJOR images.
// MODE 1 (out-proj): + bias -> f32 out.
template<int MODE>
__global__ __launch_bounds__(256, 3) void gemm_mfma(
    const ushort_t* __restrict__ Ah, const ushort_t* __restrict__ Bth,
    const float* __restrict__ bias, float* __restrict__ outF,
    ushort_t* __restrict__ Qh, ushort_t* __restrict__ Kf,
    ushort_t* __restrict__ Vf) {

    __shared__ __align__(16) ushort_t lsAh[4096], lsBh[4096];

    const int b  = blockIdx.z;
    const int n0 = blockIdx.x * 128;
    const int m0 = blockIdx.y * 128;
    const int tid = threadIdx.x;
    const int wave = tid >> 6, lane = tid & 63;
    const int l31 = lane & 31, hi5 = lane >> 5;
    const int wr = wave >> 1, wc = wave & 1;

    const int srow = lane >> 2;
    const int kswz = 8 * ((lane & 3) ^ ((lane >> 3) & 3));
    const ushort_t* gAh = Ah  + (size_t)(m0 + wave * 16 + srow) * CIN + kswz;
    const ushort_t* gBh = Bth + ((size_t)b * NN + n0 + wave * 16 + srow) * CIN + kswz;
    ushort_t* dAh = lsAh + wave * 512;
    ushort_t* dBh = lsBh + wave * 512;

    const int rswz = ((l31 >> 1) & 3) * 8;
    int offA[2][2], offB[2][2];
#pragma unroll
    for (int f = 0; f < 2; ++f)
#pragma unroll
        for (int kh = 0; kh < 2; ++kh) {
            offA[f][kh] = (wr * 64 + f * 32 + l31) * 64 + ((kh * 16 + hi5 * 8) ^ rswz) * 2;
            offB[f][kh] = (wc * 64 + f * 32 + l31) * 64 + ((kh * 16 + hi5 * 8) ^ rswz) * 2;
        }

    f32x16 acc[2][2];
#pragma unroll
    for (int i = 0; i < 2; ++i)
#pragma unroll
        for (int j = 0; j < 2; ++j)
#pragma unroll
            for (int r = 0; r < 16; ++r) acc[i][j][r] = 0.f;

    for (int k0 = 0; k0 < CIN; k0 += 32) {
        __syncthreads();
        GLDS(gAh + k0,            dAh);
        GLDS(gAh + 64 * CIN + k0, dAh + 2048);
        GLDS(gBh + k0,            dBh);
        GLDS(gBh + 64 * CIN + k0, dBh + 2048);
        __syncthreads();
#pragma unroll
        for (int kh = 0; kh < 2; ++kh) {
            bf16x8 a_h[2], b_h[2];
#pragma unroll
            for (int f = 0; f < 2; ++f) {
                a_h[f] = *(const bf16x8*)((const char*)lsAh + offA[f][kh]);
                b_h[f] = *(const bf16x8*)((const char*)lsBh + offB[f][kh]);
            }
#pragma unroll
            for (int fi = 0; fi < 2; ++fi)
#pragma unroll
                for (int fj = 0; fj < 2; ++fj)
                    acc[fi][fj] = mfma32(a_h[fi], b_h[fj], acc[fi][fj]);
        }
    }

    const int nn = n0 + wc * 64 + l31;

    if constexpr (MODE == 0) {
        const int region = m0 >> 10;  // 0=Q 1=K 2=V (uniform per block)
        if (region == 0) {
            const int head = ((m0 & 1023) >> 6) + wr;
            const size_t bh_base = (size_t)(b * HEADS + head) * NN;
#pragma unroll
            for (int fj = 0; fj < 2; ++fj) {
                const size_t rowb = (bh_base + nn + fj * 32) * DHEAD;
#pragma unroll
                for (int fi = 0; fi < 2; ++fi)
#pragma unroll
                    for (int g = 0; g < 4; ++g) {
                        ushort4v hv;
#pragma unroll
                        for (int i = 0; i < 4; ++i)
                            hv[i] = f2bf(acc[fi][fj][4 * g + i] * QSCALE_L2E);
                        *(ushort4v*)(Qh + rowb + fi * 32 + 4 * hi5 + 8 * g) = hv;
                    }
            }
        } else if (region == 1) {
            const int head = ((m0 & 1023) >> 6) + wr;
            const size_t bhk = (size_t)(b * HEADS + head);
#pragma unroll
            for (int fj = 0; fj < 2; ++fj) {
                const int j = nn + fj * 32;
                const size_t jbb = (bhk * 64 + (j >> 5)) * 4;
#pragma unroll
                for (int fi = 0; fi < 2; ++fi)
#pragma unroll
                    for (int g = 0; g < 4; ++g) {
                        ushort4v hv;
#pragma unroll
                        for (int i = 0; i < 4; ++i)
                            hv[i] = f2bf(acc[fi][fj][4 * g + i]);
                        const int c = fi * 2 + (g >> 1);
                        const int lk = (g & 1) * 32 + l31;
                        *(ushort4v*)(Kf + ((jbb + c) * 64 + lk) * 8 + 4 * hi5) = hv;
                    }
            }
        } else {
            const int ch0 = (m0 - 2048) + wr * 64;
#pragma unroll
            for (int fi = 0; fi < 2; ++fi)
#pragma unroll
                for (int fj = 0; fj < 2; ++fj) {
                    const int j = nn + fj * 32;
                    const int jb = j >> 5, kh2 = (j >> 4) & 1;
                    const int lvh = ((j >> 3) & 1) * 32;
                    const int e = j & 7;
#pragma unroll
                    for (int r = 0; r < 16; ++r) {
                        const int ch = ch0 + fi * 32 + (r & 3) + 8 * (r >> 2) + 4 * hi5;
                        const int head = ch >> 6, d = ch & 63;
                        const size_t idx =
                            (((((size_t)(b * HEADS + head) * 64 + jb) * 2 + kh2) * 2 +
                              (d >> 5)) * 64 + lvh + (d & 31)) * 8 + e;
                        Vf[idx] = f2bf(acc[fi][fj][r]);
                    }
                }
        }
    } else {
#pragma unroll
        for (int fi = 0; fi < 2; ++fi)
#pragma unroll
            for (int fj = 0; fj < 2; ++fj)
#pragma unroll
                for (int r = 0; r < 16; ++r) {
                    const int mrow = m0 + wr * 64 + fi * 32 + (r & 3) + 8 * (r >> 2) + 4 * hi5;
                    outF[((size_t)b * CIN + mrow) * NN + nn + fj * 32] =
                        acc[fi][fj][r] + bias[mrow];
                }
    }
}

// ---------------- MFMA flash attention (R18, proven 42us) ----------------
// Fragment-direct, no main-loop barriers, in-block 2-way key split.
// 512 blocks x 4 waves. Wave = (team, qpair): 64 queries as TWO independent
// 32-row chains sharing every K/V fragment load.
__global__ __launch_bounds__(256, 2) void attn_mfma(
    const ushort_t* __restrict__ Qh, const ushort_t* __restrict__ Kf,
    const ushort_t* __restrict__ Vf,
    ushort_t* __restrict__ aoth) {
    const int Lid = blockIdx.x;
    const int slot = Lid & 7, rest = Lid >> 3;
    const int bh = slot * 4 + (rest >> 4);
    const int qt = rest & 15;
    const int b = bh >> 4, h = bh & 15;
    const int w = threadIdx.x >> 6;        // 0..3
    const int team = w >> 1;               // 0: keys 0-1023, 1: 1024-2047
    const int qp = w & 1;                  // query pair within block
    const int lane = threadIdx.x & 63;
    const int l31 = lane & 31;
    const int hi5 = lane >> 5;
    const int q0a = qt * 128 + qp * 64;
    const int q0b = q0a + 32;

    __shared__ float oS[128 * 65];
    __shared__ float lS[128];

    // Q fragments for both chains (one-time gathers)
    bf16x8 qfa[4], qfb[4];
    {
        const ushort_t* qa = Qh + ((size_t)bh * NN + q0a + l31) * DHEAD + hi5 * 8;
        const ushort_t* qb = Qh + ((size_t)bh * NN + q0b + l31) * DHEAD + hi5 * 8;
#pragma unroll
        for (int c = 0; c < 4; ++c) {
            qfa[c] = *(const bf16x8*)(qa + c * 16);
            qfb[c] = *(const bf16x8*)(qb + c * 16);
        }
    }

    // fragment streams: 2048 elems (4KB) per 32-key block for each of K,V
    const ushort_t* kp0 = Kf + ((size_t)bh * 64 + team * 32) * 2048 + lane * 8;
    const ushort_t* vp0 = Vf + ((size_t)bh * 64 + team * 32) * 2048 + lane * 8;

    f32x16 o0a, o1a, o0b, o1b, zz;
#pragma unroll
    for (int r = 0; r < 16; ++r) {
        o0a[r] = 0.f; o1a[r] = 0.f; o0b[r] = 0.f; o1b[r] = 0.f; zz[r] = 0.f;
    }
    float la = 0.f, lb = 0.f;

#define ATTN_LOAD(P, JB)                                                       \
    {                                                                          \
        const ushort_t* kq_ = kp0 + (size_t)(JB) * 2048;                       \
        const ushort_t* vq_ = vp0 + (size_t)(JB) * 2048;                       \
        P##k0 = *(const bf16x8*)(kq_);                                         \
        P##k1 = *(const bf16x8*)(kq_ + 512);                                   \
        P##k2 = *(const bf16x8*)(kq_ + 1024);                                  \
        P##k3 = *(const bf16x8*)(kq_ + 1536);                                  \
        P##v0 = *(const bf16x8*)(vq_);                                         \
        P##v1 = *(const bf16x8*)(vq_ + 512);                                   \
        P##v2 = *(const bf16x8*)(vq_ + 1024);                                  \
        P##v3 = *(const bf16x8*)(vq_ + 1536);                                  \
    }

    // one softmax+pack+PV chain
#define ATTN_CHAIN(SS, V0, V1, V2, V3, O0, O1, LACC)                           \
    {                                                                          \
        f32x16 s;                                                              \
        _Pragma("unroll") for (int r = 0; r < 16; ++r)                         \
            s[r] = __builtin_amdgcn_exp2f(SS[r]);                              \
        float t0 = (s[0] + s[1]) + (s[2] + s[3]);                              \
        float t1 = (s[4] + s[5]) + (s[6] + s[7]);                              \
        float t2 = (s[8] + s[9]) + (s[10] + s[11]);                            \
        float t3 = (s[12] + s[13]) + (s[14] + s[15]);                          \
        LACC += (t0 + t1) + (t2 + t3);                                         \
        unsigned Q0 = cvt_pk_bf16(s[0], s[1]);                                 \
        unsigned Q1 = cvt_pk_bf16(s[2], s[3]);                                 \
        unsigned Q2 = cvt_pk_bf16(s[4], s[5]);                                 \
        unsigned Q3 = cvt_pk_bf16(s[6], s[7]);                                 \
        asm("v_permlane32_swap_b32 %0, %1" : "+v"(Q0), "+v"(Q2));              \
        asm("v_permlane32_swap_b32 %0, %1" : "+v"(Q1), "+v"(Q3));              \
        unsigned R0 = cvt_pk_bf16(s[8], s[9]);                                 \
        unsigned R1 = cvt_pk_bf16(s[10], s[11]);                               \
        unsigned R2 = cvt_pk_bf16(s[12], s[13]);                               \
        unsigned R3 = cvt_pk_bf16(s[14], s[15]);                               \
        asm("v_permlane32_swap_b32 %0, %1" : "+v"(R0), "+v"(R2));              \
        asm("v_permlane32_swap_b32 %0, %1" : "+v"(R1), "+v"(R3));              \
        U4 thA; thA.u[0] = Q0; thA.u[1] = Q1; thA.u[2] = Q2; thA.u[3] = Q3;    \
        U4 thB; thB.u[0] = R0; thB.u[1] = R1; thB.u[2] = R2; thB.u[3] = R3;    \
        bf16x8 pB0 = thA.v, pB1 = thB.v;                                       \
        __builtin_amdgcn_s_setprio(1);                                         \
        O0 = mfma32(V0, pB0, O0);                                              \
        O1 = mfma32(V1, pB0, O1);                                              \
        O0 = mfma32(V2, pB1, O0);                                              \
        O1 = mfma32(V3, pB1, O1);                                              \
        __builtin_amdgcn_s_setprio(0);                                         \
    }

#define ATTN_STEP2(K0, K1, K2, K3, V0, V1, V2, V3)                             \
    {                                                                          \
        __builtin_amdgcn_s_setprio(1);                                         \
        f32x16 sSa = mfma32(K0, qfa[0], zz);                                   \
        sSa = mfma32(K1, qfa[1], sSa);                                         \
        sSa = mfma32(K2, qfa[2], sSa);                                         \
        sSa = mfma32(K3, qfa[3], sSa);                                         \
        f32x16 sSb = mfma32(K0, qfb[0], zz);                                   \
        sSb = mfma32(K1, qfb[1], sSb);                                         \
        sSb = mfma32(K2, qfb[2], sSb);                                         \
        sSb = mfma32(K3, qfb[3], sSb);                                         \
        __builtin_amdgcn_s_setprio(0);                                         \
        ATTN_CHAIN(sSa, V0, V1, V2, V3, o0a, o1a, la);                         \
        ATTN_CHAIN(sSb, V0, V1, V2, V3, o0b, o1b, lb);                         \
    }

    bf16x8 ak0, ak1, ak2, ak3, av0, av1, av2, av3;
    bf16x8 bk0, bk1, bk2, bk3, bv0, bv1, bv2, bv3;
    ATTN_LOAD(a, 0);
#pragma unroll 1
    for (int jb = 0; jb < 32; jb += 2) {
        ATTN_LOAD(b, jb + 1);
        ATTN_STEP2(ak0, ak1, ak2, ak3, av0, av1, av2, av3);
        ATTN_LOAD(a, (jb + 2) & 31);
        ATTN_STEP2(bk0, bk1, bk2, bk3, bv0, bv1, bv2, bv3);
    }
#undef ATTN_LOAD
#undef ATTN_CHAIN
#undef ATTN_STEP2

    // ---- in-block combine (m=0 -> pure add), single barrier ----
    la += __shfl_xor(la, 32);
    lb += __shfl_xor(lb, 32);
    const int qA = qp * 64 + l31;       // row within block's 128 queries
    const int qB = qA + 32;
    if (team == 1) {
#pragma unroll
        for (int dt = 0; dt < 2; ++dt)
#pragma unroll
            for (int r = 0; r < 16; ++r) {
                const int d = dt * 32 + (r & 3) + 8 * (r >> 2) + 4 * hi5;
                oS[qA * 65 + d] = dt ? o1a[r] : o0a[r];
                oS[qB * 65 + d] = dt ? o1b[r] : o0b[r];
            }
        if (hi5 == 0) { lS[qA] = la; lS[qB] = lb; }
    }
    __syncthreads();
    if (team == 0) {
        const float invlA = 1.0f / (la + lS[qA]);
        const float invlB = 1.0f / (lb + lS[qB]);
        const size_t rowa = ((size_t)b * NN + q0a + l31) * HDIM + h * DHEAD;
        const size_t rowbb = ((size_t)b * NN + q0b + l31) * HDIM + h * DHEAD;
#pragma unroll
        for (int dt = 0; dt < 2; ++dt)
#pragma unroll
            for (int g = 0; g < 4; ++g) {
                ushort4v hva, hvb;
#pragma unroll
                for (int i = 0; i < 4; ++i) {
                    const int r = 4 * g + i;
                    const int d = dt * 32 + i + 8 * g + 4 * hi5;
                    float fa = ((dt ? o1a[r] : o0a[r]) + oS[qA * 65 + d]) * invlA;
                    float fb = ((dt ? o1b[r] : o0b[r]) + oS[qB * 65 + d]) * invlB;
                    hva[i] = f2bf(fa);
                    hvb[i] = f2bf(fb);
                }
                const size_t oo = dt * 32 + 8 * g + 4 * hi5;
                *(ushort4v*)(aoth + rowa + oo) = hva;
                *(ushort4v*)(aoth + rowbb + oo) = hvb;
            }
    }
}

// ---------------- launch ----------------
extern "C" void kernel_launch(void* const* d_in, const int* in_sizes, int n_in,
                              void* d_out, int out_size, void* d_ws, size_t ws_size,
                              hipStream_t stream) {
    const float* x     = (const float*)d_in[0];
    const float* w_qkv = (const float*)d_in[1];
    const float* w_out = (const float*)d_in[2];
    const float* b_out = (const float*)d_in[3];
    float* out = (float*)d_out;

    ushort_t* ws_u = (ushort_t*)d_ws;
    ushort_t* Qh = ws_u;
    ushort_t* Kf = Qh + QSZ;                   // fragment-major K (8MB)
    ushort_t* Vf = Kf + QSZ;                   // fragment-major V (8MB)
    ushort_t* woh = ws_u + 3 * QSZ;            // w_out hi (free region)
    ushort_t* shared_u = ws_u + 6 * QSZ;       // wq hi (phase A), aot hi (phase B)
    ushort_t* wqh = shared_u;
    ushort_t* aoth = shared_u;
    ushort_t* xth = (ushort_t*)d_out;          // x^T bf16 in d_out (dead later)

    if (ws_size < (6 * QSZ + 2 * (size_t)BATCH * NN * CIN) * sizeof(ushort_t)) return;

    // 1) fused prep: w_qkv/w_out bf16 + x^T (concurrent, one launch)
    prep_fused<<<6144, 256, 0, stream>>>(w_qkv, wqh, O3 * CIN / 8,
                                         w_out, woh, CIN * HDIM / 8, x, xth);

    // 2) QKV projection (plain bf16) -> Q / Kf / Vf (fragment-major K,V)
    gemm_mfma<0><<<dim3(NN / 128, O3 / 128, BATCH), 256, 0, stream>>>(
        wqh, xth, nullptr, nullptr, Qh, Kf, Vf);

    // 3) flash attention (2 chains/wave, fragment-direct) -> aot hi
    attn_mfma<<<dim3(512), 256, 0, stream>>>(Qh, Kf, Vf, aoth);

    // 4) output projection (plain bf16 1-term) + bias -> out f32
    gemm_mfma<1><<<dim3(NN / 128, HDIM / 128, BATCH), 256, 0, stream>>>(
        woh, aoth, b_out, out, nullptr, nullptr, nullptr);
}